// Round 2
// baseline (1693.489 us; speedup 1.0000x reference)
//
#include <hip/hip_runtime.h>
#include <hip/hip_bf16.h>

typedef float f32x4 __attribute__((ext_vector_type(4)));
typedef short bf16x8 __attribute__((ext_vector_type(8)));
typedef unsigned short ushort_t;

#define EPSV 1e-5f

__device__ __forceinline__ ushort_t bfu(float f) {
  union { __hip_bfloat16 h; ushort_t u; } cv;
  cv.h = __float2bfloat16(f);
  return cv.u;
}

__device__ __forceinline__ f32x4 mfma16(bf16x8 a, bf16x8 b, f32x4 c) {
  return __builtin_amdgcn_mfma_f32_16x16x32_bf16(a, b, c, 0, 0, 0);
}

// ---------------------------------------------------------------------------
// GEMM: C[M,N] = A[M,K] @ B[N,K]^T   (A,B fp32 in global, bf16 MFMA, C fp32)
// BM=128, BN=64, BK=64, 256 threads (4 waves in 2x2), st-swizzled bf16 LDS.
// Biases intentionally omitted (BatchNorm cancels them exactly).
// ---------------------------------------------------------------------------
__global__ __launch_bounds__(256, 2) void gemm_bf16(
    const float* __restrict__ A, const float* __restrict__ B,
    float* __restrict__ C, int M, int N, int K)
{
  constexpr int BM = 128, BN = 64, BK = 64;
  __shared__ ushort_t As[BM * BK];
  __shared__ ushort_t Bs[BN * BK];
  const int tid  = threadIdx.x;
  const int lane = tid & 63;
  const int wave = tid >> 6;
  const int wr = wave >> 1, wc = wave & 1;       // wave grid 2x2 over 128x64
  const int mb = blockIdx.x * BM, nb = blockIdx.y * BN;

  f32x4 acc[4][2];
#pragma unroll
  for (int i = 0; i < 4; ++i)
#pragma unroll
    for (int j = 0; j < 2; ++j) acc[i][j] = f32x4{0.f, 0.f, 0.f, 0.f};

  for (int k0 = 0; k0 < K; k0 += BK) {
    // ---- stage A tile 128x64 (fp32 -> bf16, swizzled) ----
#pragma unroll
    for (int it = 0; it < 4; ++it) {
      int idx = tid + it * 256;          // 0..1023, 8 elems each
      int r = idx >> 3, kc = (idx & 7) << 3;
      const float* src = A + (size_t)(mb + r) * K + k0 + kc;
      float4 f0 = *(const float4*)src;
      float4 f1 = *(const float4*)(src + 4);
      bf16x8 v;
      v[0] = (short)bfu(f0.x); v[1] = (short)bfu(f0.y);
      v[2] = (short)bfu(f0.z); v[3] = (short)bfu(f0.w);
      v[4] = (short)bfu(f1.x); v[5] = (short)bfu(f1.y);
      v[6] = (short)bfu(f1.z); v[7] = (short)bfu(f1.w);
      int off = ((r * BK + kc) << 1) ^ ((r & 7) << 4);
      *reinterpret_cast<bf16x8*>(reinterpret_cast<char*>(As) + off) = v;
    }
    // ---- stage B tile 64x64 ----
#pragma unroll
    for (int it = 0; it < 2; ++it) {
      int idx = tid + it * 256;          // 0..511
      int r = idx >> 3, kc = (idx & 7) << 3;
      const float* src = B + (size_t)(nb + r) * K + k0 + kc;
      float4 f0 = *(const float4*)src;
      float4 f1 = *(const float4*)(src + 4);
      bf16x8 v;
      v[0] = (short)bfu(f0.x); v[1] = (short)bfu(f0.y);
      v[2] = (short)bfu(f0.z); v[3] = (short)bfu(f0.w);
      v[4] = (short)bfu(f1.x); v[5] = (short)bfu(f1.y);
      v[6] = (short)bfu(f1.z); v[7] = (short)bfu(f1.w);
      int off = ((r * BK + kc) << 1) ^ ((r & 7) << 4);
      *reinterpret_cast<bf16x8*>(reinterpret_cast<char*>(Bs) + off) = v;
    }
    __syncthreads();
#pragma unroll
    for (int kk = 0; kk < BK; kk += 32) {
      const int kb = (kk + ((lane >> 4) << 3)) << 1;   // byte offset of k
      bf16x8 af[4], bfr[2];
#pragma unroll
      for (int mf = 0; mf < 4; ++mf) {
        int r = wr * 64 + mf * 16 + (lane & 15);
        int off = (r * (BK * 2) + kb) ^ ((r & 7) << 4);
        af[mf] = *reinterpret_cast<const bf16x8*>(reinterpret_cast<const char*>(As) + off);
      }
#pragma unroll
      for (int nf = 0; nf < 2; ++nf) {
        int r = wc * 32 + nf * 16 + (lane & 15);
        int off = (r * (BK * 2) + kb) ^ ((r & 7) << 4);
        bfr[nf] = *reinterpret_cast<const bf16x8*>(reinterpret_cast<const char*>(Bs) + off);
      }
#pragma unroll
      for (int mf = 0; mf < 4; ++mf)
#pragma unroll
        for (int nf = 0; nf < 2; ++nf)
          acc[mf][nf] = mfma16(af[mf], bfr[nf], acc[mf][nf]);
    }
    __syncthreads();
  }
  // epilogue: C/D layout col=lane&15, row=(lane>>4)*4+i
#pragma unroll
  for (int mf = 0; mf < 4; ++mf)
#pragma unroll
    for (int nf = 0; nf < 2; ++nf) {
      int col = nb + wc * 32 + nf * 16 + (lane & 15);
      int rbase = mb + wr * 64 + mf * 16 + ((lane >> 4) << 2);
#pragma unroll
      for (int i = 0; i < 4; ++i)
        C[(size_t)(rbase + i) * N + col] = acc[mf][nf][i];
    }
}

// ---------------------------------------------------------------------------
// column sums / sums-of-squares for BatchNorm (partial blocks + atomics)
// grid: (N/64, M/256), block 256
// ---------------------------------------------------------------------------
__global__ __launch_bounds__(256) void col_stats(
    const float* __restrict__ H, float* __restrict__ stats, int M, int N)
{
  int c = blockIdx.x * 64 + (threadIdx.x & 63);
  int rEnd = blockIdx.y * 256 + 256;
  float s = 0.f, q = 0.f;
  for (int r = blockIdx.y * 256 + (threadIdx.x >> 6); r < rEnd; r += 4) {
    float v = H[(size_t)r * N + c];
    s += v; q += v * v;
  }
  atomicAdd(&stats[c], s);
  atomicAdd(&stats[N + c], q);
}

// BN (training stats) + ReLU, in place. N is a power of two.
__global__ __launch_bounds__(256) void bn_apply(
    float* __restrict__ H, const float* __restrict__ stats,
    const float* __restrict__ g, const float* __restrict__ be, int M, int N)
{
  float invM = 1.0f / (float)M;
  int total = M * N;
  for (int idx = blockIdx.x * 256 + threadIdx.x; idx < total;
       idx += gridDim.x * 256) {
    int c = idx & (N - 1);
    float mean = stats[c] * invM;
    float var  = stats[N + c] * invM - mean * mean;
    float sc   = g[c] / sqrtf(var + EPSV);
    float sh   = be[c] - mean * sc;
    float v = H[idx] * sc + sh;
    H[idx] = v > 0.f ? v : 0.f;
  }
}

// ---------------------------------------------------------------------------
// agg[M,64] += (adj*alpha)[M,K] @ h[K,64]; deg[M] += rowsum(adj).
// A direct-to-reg (adj?alpha:0 -> bf16), B (h) staged fp32->bf16 in LDS
// as [col][k] (transposed) so frags read 8 consecutive k. Split-K + atomics.
// grid: (M/128, K/kChunk), block 256 (4 waves, 32 rows each)
// ---------------------------------------------------------------------------
__global__ __launch_bounds__(256, 2) void agg_kernel(
    const int* __restrict__ adj, int adjStride,
    const float* __restrict__ alpha, int alphaStride,
    const float* __restrict__ h, float* __restrict__ agg,
    float* __restrict__ deg, int kChunk)
{
  __shared__ ushort_t Bs[64 * 64];
  const int tid = threadIdx.x, lane = tid & 63, wave = tid >> 6;
  const int mb = blockIdx.x * 128;
  const int kStart = blockIdx.y * kChunk;
  const int rowBase = mb + wave * 32;

  f32x4 acc[2][4];
#pragma unroll
  for (int i = 0; i < 2; ++i)
#pragma unroll
    for (int j = 0; j < 4; ++j) acc[i][j] = f32x4{0.f, 0.f, 0.f, 0.f};
  int degAcc[2] = {0, 0};

  for (int k0 = kStart; k0 < kStart + kChunk; k0 += 64) {
    {   // stage h[k0..k0+64][0..64] -> Bs[c][k]
      int c = tid & 63, r0 = (tid >> 6) * 16;
#pragma unroll
      for (int half = 0; half < 2; ++half) {
        bf16x8 v;
#pragma unroll
        for (int j = 0; j < 8; ++j)
          v[j] = (short)bfu(h[(size_t)(k0 + r0 + half * 8 + j) * 64 + c]);
        int off = ((c * 64 + r0 + half * 8) << 1) ^ ((c & 7) << 4);
        *reinterpret_cast<bf16x8*>(reinterpret_cast<char*>(Bs) + off) = v;
      }
    }
    __syncthreads();
#pragma unroll
    for (int kk = 0; kk < 64; kk += 32) {
      int kb = (lane >> 4) << 3;
      int kg = k0 + kk + kb;
      bf16x8 af[2];
#pragma unroll
      for (int mf = 0; mf < 2; ++mf) {
        int row = rowBase + mf * 16 + (lane & 15);
        const int*   ap = adj   + (size_t)row * adjStride   + kg;
        const float* lp = alpha + (size_t)row * alphaStride + kg;
        int4 a0 = *(const int4*)ap;
        int4 a1 = *(const int4*)(ap + 4);
        float4 f0 = *(const float4*)lp;
        float4 f1 = *(const float4*)(lp + 4);
        degAcc[mf] += a0.x + a0.y + a0.z + a0.w + a1.x + a1.y + a1.z + a1.w;
        bf16x8 v;
        v[0] = a0.x ? (short)bfu(f0.x) : (short)0;
        v[1] = a0.y ? (short)bfu(f0.y) : (short)0;
        v[2] = a0.z ? (short)bfu(f0.z) : (short)0;
        v[3] = a0.w ? (short)bfu(f0.w) : (short)0;
        v[4] = a1.x ? (short)bfu(f1.x) : (short)0;
        v[5] = a1.y ? (short)bfu(f1.y) : (short)0;
        v[6] = a1.z ? (short)bfu(f1.z) : (short)0;
        v[7] = a1.w ? (short)bfu(f1.w) : (short)0;
        af[mf] = v;
      }
      bf16x8 br[4];
#pragma unroll
      for (int nf = 0; nf < 4; ++nf) {
        int c = nf * 16 + (lane & 15);
        int off = ((c * 64 + kk + kb) << 1) ^ ((c & 7) << 4);
        br[nf] = *reinterpret_cast<const bf16x8*>(reinterpret_cast<const char*>(Bs) + off);
      }
#pragma unroll
      for (int mf = 0; mf < 2; ++mf)
#pragma unroll
        for (int nf = 0; nf < 4; ++nf)
          acc[mf][nf] = mfma16(af[mf], br[nf], acc[mf][nf]);
    }
    __syncthreads();
  }
  // deg: reduce over the 4 quarter-wave k-groups, one atomic per row
#pragma unroll
  for (int mf = 0; mf < 2; ++mf) {
    int s = degAcc[mf];
    s += __shfl_xor(s, 16);
    s += __shfl_xor(s, 32);
    if (lane < 16) atomicAdd(&deg[rowBase + mf * 16 + lane], (float)s);
  }
#pragma unroll
  for (int mf = 0; mf < 2; ++mf)
#pragma unroll
    for (int nf = 0; nf < 4; ++nf) {
      int col = nf * 16 + (lane & 15);
      int rbase = rowBase + mf * 16 + ((lane >> 4) << 2);
#pragma unroll
      for (int i = 0; i < 4; ++i)
        atomicAdd(&agg[(size_t)(rbase + i) * 64 + col], acc[mf][nf][i]);
    }
}

// ---------------------------------------------------------------------------
// fused classifier: new = agg*W/deg + h ; logits[c] += dot(new, cw[c])
// ---------------------------------------------------------------------------
__global__ __launch_bounds__(256) void fused_dot(
    const float* __restrict__ agg1, const float* __restrict__ h1,
    const float* __restrict__ deg1,
    const float* __restrict__ agg2, const float* __restrict__ h2,
    const float* __restrict__ deg2,
    const float* __restrict__ Wp, const float* __restrict__ cw,
    float* __restrict__ logits)
{
  const float w00 = Wp[0];
  const int n1 = 8192 * 64;
  const int ntot = (8192 + 4096) * 64;
  float a0 = 0.f, a1 = 0.f;
  for (int j = blockIdx.x * 256 + threadIdx.x; j < ntot;
       j += gridDim.x * 256) {
    float v;
    if (j < n1) {
      v = agg1[j] * w00 / deg1[j >> 6] + h1[j];
    } else {
      int j2 = j - n1;
      v = agg2[j2] * w00 / deg2[j2 >> 6] + h2[j2];
    }
    a0 += v * cw[j];
    a1 += v * cw[ntot + j];
  }
#pragma unroll
  for (int o = 32; o > 0; o >>= 1) {
    a0 += __shfl_down(a0, o);
    a1 += __shfl_down(a1, o);
  }
  __shared__ float s0[4], s1[4];
  int lane = threadIdx.x & 63, wave = threadIdx.x >> 6;
  if (lane == 0) { s0[wave] = a0; s1[wave] = a1; }
  __syncthreads();
  if (threadIdx.x == 0) {
    atomicAdd(&logits[0], s0[0] + s0[1] + s0[2] + s0[3]);
    atomicAdd(&logits[1], s1[0] + s1[1] + s1[2] + s1[3]);
  }
}

__global__ void finalize(const float* __restrict__ logits,
                         const float* __restrict__ cb, float* __restrict__ out)
{
  if (threadIdx.x == 0) {
    float l0 = logits[0] + cb[0];
    float l1 = logits[1] + cb[1];
    float m = fmaxf(l0, l1);
    float e0 = expf(l0 - m), e1 = expf(l1 - m);
    float inv = 1.f / (e0 + e1);
    out[0] = e0 * inv;
    out[1] = e1 * inv;
  }
}

// ---------------------------------------------------------------------------
extern "C" void kernel_launch(void* const* d_in, const int* in_sizes, int n_in,
                              void* d_out, int out_size, void* d_ws,
                              size_t ws_size, hipStream_t stream)
{
  const float* x1    = (const float*)d_in[0];
  const float* x2    = (const float*)d_in[1];
  const int*   adj1  = (const int*)d_in[2];
  const int*   adj2  = (const int*)d_in[3];
  const float* p1w1  = (const float*)d_in[4];
  const float* p1g1  = (const float*)d_in[6];
  const float* p1be1 = (const float*)d_in[7];
  const float* p1w2  = (const float*)d_in[8];
  const float* p1g2  = (const float*)d_in[10];
  const float* p1be2 = (const float*)d_in[11];
  const float* p1w3  = (const float*)d_in[12];
  const float* p1g3  = (const float*)d_in[14];
  const float* p1be3 = (const float*)d_in[15];
  const float* p2w1  = (const float*)d_in[16];
  const float* p2g1  = (const float*)d_in[18];
  const float* p2be1 = (const float*)d_in[19];
  const float* p2w2  = (const float*)d_in[20];
  const float* p2g2  = (const float*)d_in[22];
  const float* p2be2 = (const float*)d_in[23];
  const float* p2w3  = (const float*)d_in[24];
  const float* p2g3  = (const float*)d_in[26];
  const float* p2be3 = (const float*)d_in[27];
  const float* Wp     = (const float*)d_in[28];
  const float* alpha1 = (const float*)d_in[29];
  const float* cw     = (const float*)d_in[31];
  const float* cb     = (const float*)d_in[32];
  float* out = (float*)d_out;

  float* w    = (float*)d_ws;
  float* H1a  = w;                  // 8192*256
  float* H1b  = H1a + 2097152;      // 8192*128
  float* h1   = H1b + 1048576;      // 8192*64
  float* H2a  = h1  + 524288;       // 4096*256
  float* H2b  = H2a + 1048576;      // 4096*128
  float* h2   = H2b + 524288;       // 4096*64
  float* agg1 = h2  + 262144;       // 8192*64   (zeroed region starts here)
  float* agg2 = agg1 + 524288;      // 4096*64
  float* deg1 = agg2 + 262144;      // 8192
  float* deg2 = deg1 + 8192;        // 4096
  float* st   = deg2 + 4096;        // 6*512
  float* logits = st + 3072;        // 8

  size_t zeroBytes = (size_t)(524288 + 262144 + 8192 + 4096 + 3072 + 8) * 4;
  hipMemsetAsync(agg1, 0, zeroBytes, stream);

  // ---- branch 1 encoder ----
  gemm_bf16<<<dim3(64, 4), 256, 0, stream>>>(x1, p1w1, H1a, 8192, 256, 8192);
  col_stats<<<dim3(4, 32), 256, 0, stream>>>(H1a, st + 0 * 512, 8192, 256);
  bn_apply<<<2048, 256, 0, stream>>>(H1a, st + 0 * 512, p1g1, p1be1, 8192, 256);
  gemm_bf16<<<dim3(64, 2), 256, 0, stream>>>(H1a, p1w2, H1b, 8192, 128, 256);
  col_stats<<<dim3(2, 32), 256, 0, stream>>>(H1b, st + 1 * 512, 8192, 128);
  bn_apply<<<1024, 256, 0, stream>>>(H1b, st + 1 * 512, p1g2, p1be2, 8192, 128);
  gemm_bf16<<<dim3(64, 1), 256, 0, stream>>>(H1b, p1w3, h1, 8192, 64, 128);
  col_stats<<<dim3(1, 32), 256, 0, stream>>>(h1, st + 2 * 512, 8192, 64);
  bn_apply<<<512, 256, 0, stream>>>(h1, st + 2 * 512, p1g3, p1be3, 8192, 64);

  // ---- branch 2 encoder ----
  gemm_bf16<<<dim3(32, 4), 256, 0, stream>>>(x2, p2w1, H2a, 4096, 256, 4096);
  col_stats<<<dim3(4, 16), 256, 0, stream>>>(H2a, st + 3 * 512, 4096, 256);
  bn_apply<<<1024, 256, 0, stream>>>(H2a, st + 3 * 512, p2g1, p2be1, 4096, 256);
  gemm_bf16<<<dim3(32, 2), 256, 0, stream>>>(H2a, p2w2, H2b, 4096, 128, 256);
  col_stats<<<dim3(2, 16), 256, 0, stream>>>(H2b, st + 4 * 512, 4096, 128);
  bn_apply<<<512, 256, 0, stream>>>(H2b, st + 4 * 512, p2g2, p2be2, 4096, 128);
  gemm_bf16<<<dim3(32, 1), 256, 0, stream>>>(H2b, p2w3, h2, 4096, 64, 128);
  col_stats<<<dim3(1, 16), 256, 0, stream>>>(h2, st + 5 * 512, 4096, 64);
  bn_apply<<<256, 256, 0, stream>>>(h2, st + 5 * 512, p2g3, p2be3, 4096, 64);

  // ---- attention aggregation (fused deg) ----
  agg_kernel<<<dim3(64, 4), 256, 0, stream>>>(adj1, 8192, alpha1, 8192,
                                              h1, agg1, deg1, 2048);
  // NB: reference reuses alpha1[:4096,:4096] for graph 2 (source bug kept)
  agg_kernel<<<dim3(32, 8), 256, 0, stream>>>(adj2, 4096, alpha1, 8192,
                                              h2, agg2, deg2, 512);

  // ---- fused classifier + softmax ----
  fused_dot<<<1024, 256, 0, stream>>>(agg1, h1, deg1, agg2, h2, deg2,
                                      Wp, cw, logits);
  finalize<<<1, 64, 0, stream>>>(logits, cb, out);
}

// Round 3
// 1345.882 us; speedup vs baseline: 1.2583x; 1.2583x over previous
//
#include <hip/hip_runtime.h>
#include <hip/hip_bf16.h>

typedef float f32x4 __attribute__((ext_vector_type(4)));
typedef short bf16x8 __attribute__((ext_vector_type(8)));
typedef unsigned short ushort_t;

#define EPSV 1e-5f

__device__ __forceinline__ ushort_t bfu(float f) {
  union { __hip_bfloat16 h; ushort_t u; } cv;
  cv.h = __float2bfloat16(f);
  return cv.u;
}

__device__ __forceinline__ f32x4 mfma16(bf16x8 a, bf16x8 b, f32x4 c) {
  return __builtin_amdgcn_mfma_f32_16x16x32_bf16(a, b, c, 0, 0, 0);
}

// ---------------------------------------------------------------------------
// GEMM: C[M,N] (+)= A[M,K] @ B[N,K]^T  (A,B fp32 in global, bf16 MFMA, C fp32)
// BM=128, BN=64, BK=64, 256 threads (4 waves in 2x2), st-swizzled bf16 LDS.
// Split-K over blockIdx.z (kChunk each); epilogue atomicAdd when gridDim.z>1.
// Biases intentionally omitted (BatchNorm cancels them exactly).
// ---------------------------------------------------------------------------
__global__ __launch_bounds__(256, 2) void gemm_bf16(
    const float* __restrict__ A, const float* __restrict__ B,
    float* __restrict__ C, int M, int N, int K, int kChunk)
{
  constexpr int BM = 128, BN = 64, BK = 64;
  __shared__ ushort_t As[BM * BK];
  __shared__ ushort_t Bs[BN * BK];
  const int tid  = threadIdx.x;
  const int lane = tid & 63;
  const int wave = tid >> 6;
  const int wr = wave >> 1, wc = wave & 1;       // wave grid 2x2 over 128x64
  const int mb = blockIdx.x * BM, nb = blockIdx.y * BN;
  const int kStart = blockIdx.z * kChunk;
  const int kEnd = kStart + kChunk;

  f32x4 acc[4][2];
#pragma unroll
  for (int i = 0; i < 4; ++i)
#pragma unroll
    for (int j = 0; j < 2; ++j) acc[i][j] = f32x4{0.f, 0.f, 0.f, 0.f};

  for (int k0 = kStart; k0 < kEnd; k0 += BK) {
    // ---- stage A tile 128x64 (fp32 -> bf16, swizzled) ----
#pragma unroll
    for (int it = 0; it < 4; ++it) {
      int idx = tid + it * 256;          // 0..1023, 8 elems each
      int r = idx >> 3, kc = (idx & 7) << 3;
      const float* src = A + (size_t)(mb + r) * K + k0 + kc;
      float4 f0 = *(const float4*)src;
      float4 f1 = *(const float4*)(src + 4);
      bf16x8 v;
      v[0] = (short)bfu(f0.x); v[1] = (short)bfu(f0.y);
      v[2] = (short)bfu(f0.z); v[3] = (short)bfu(f0.w);
      v[4] = (short)bfu(f1.x); v[5] = (short)bfu(f1.y);
      v[6] = (short)bfu(f1.z); v[7] = (short)bfu(f1.w);
      int off = ((r * BK + kc) << 1) ^ ((r & 7) << 4);
      *reinterpret_cast<bf16x8*>(reinterpret_cast<char*>(As) + off) = v;
    }
    // ---- stage B tile 64x64 ----
#pragma unroll
    for (int it = 0; it < 2; ++it) {
      int idx = tid + it * 256;          // 0..511
      int r = idx >> 3, kc = (idx & 7) << 3;
      const float* src = B + (size_t)(nb + r) * K + k0 + kc;
      float4 f0 = *(const float4*)src;
      float4 f1 = *(const float4*)(src + 4);
      bf16x8 v;
      v[0] = (short)bfu(f0.x); v[1] = (short)bfu(f0.y);
      v[2] = (short)bfu(f0.z); v[3] = (short)bfu(f0.w);
      v[4] = (short)bfu(f1.x); v[5] = (short)bfu(f1.y);
      v[6] = (short)bfu(f1.z); v[7] = (short)bfu(f1.w);
      int off = ((r * BK + kc) << 1) ^ ((r & 7) << 4);
      *reinterpret_cast<bf16x8*>(reinterpret_cast<char*>(Bs) + off) = v;
    }
    __syncthreads();
#pragma unroll
    for (int kk = 0; kk < BK; kk += 32) {
      const int kb = (kk + ((lane >> 4) << 3)) << 1;   // byte offset of k
      bf16x8 af[4], bfr[2];
#pragma unroll
      for (int mf = 0; mf < 4; ++mf) {
        int r = wr * 64 + mf * 16 + (lane & 15);
        int off = (r * (BK * 2) + kb) ^ ((r & 7) << 4);
        af[mf] = *reinterpret_cast<const bf16x8*>(reinterpret_cast<const char*>(As) + off);
      }
#pragma unroll
      for (int nf = 0; nf < 2; ++nf) {
        int r = wc * 32 + nf * 16 + (lane & 15);
        int off = (r * (BK * 2) + kb) ^ ((r & 7) << 4);
        bfr[nf] = *reinterpret_cast<const bf16x8*>(reinterpret_cast<const char*>(Bs) + off);
      }
#pragma unroll
      for (int mf = 0; mf < 4; ++mf)
#pragma unroll
        for (int nf = 0; nf < 2; ++nf)
          acc[mf][nf] = mfma16(af[mf], bfr[nf], acc[mf][nf]);
    }
    __syncthreads();
  }
  // epilogue: C/D layout col=lane&15, row=(lane>>4)*4+i
  const bool split = (gridDim.z > 1);
#pragma unroll
  for (int mf = 0; mf < 4; ++mf)
#pragma unroll
    for (int nf = 0; nf < 2; ++nf) {
      int col = nb + wc * 32 + nf * 16 + (lane & 15);
      int rbase = mb + wr * 64 + mf * 16 + ((lane >> 4) << 2);
      if (split) {
#pragma unroll
        for (int i = 0; i < 4; ++i)
          atomicAdd(&C[(size_t)(rbase + i) * N + col], acc[mf][nf][i]);
      } else {
#pragma unroll
        for (int i = 0; i < 4; ++i)
          C[(size_t)(rbase + i) * N + col] = acc[mf][nf][i];
      }
    }
}

// ---------------------------------------------------------------------------
// column sums / sums-of-squares for BatchNorm (partial blocks + atomics)
// grid: (N/64, M/256), block 256
// ---------------------------------------------------------------------------
__global__ __launch_bounds__(256) void col_stats(
    const float* __restrict__ H, float* __restrict__ stats, int M, int N)
{
  int c = blockIdx.x * 64 + (threadIdx.x & 63);
  int rEnd = blockIdx.y * 256 + 256;
  float s = 0.f, q = 0.f;
  for (int r = blockIdx.y * 256 + (threadIdx.x >> 6); r < rEnd; r += 4) {
    float v = H[(size_t)r * N + c];
    s += v; q += v * v;
  }
  atomicAdd(&stats[c], s);
  atomicAdd(&stats[N + c], q);
}

// BN (training stats) + ReLU, in place. N is a power of two.
__global__ __launch_bounds__(256) void bn_apply(
    float* __restrict__ H, const float* __restrict__ stats,
    const float* __restrict__ g, const float* __restrict__ be, int M, int N)
{
  float invM = 1.0f / (float)M;
  int total = M * N;
  for (int idx = blockIdx.x * 256 + threadIdx.x; idx < total;
       idx += gridDim.x * 256) {
    int c = idx & (N - 1);
    float mean = stats[c] * invM;
    float var  = stats[N + c] * invM - mean * mean;
    float sc   = g[c] / sqrtf(var + EPSV);
    float sh   = be[c] - mean * sc;
    float v = H[idx] * sc + sh;
    H[idx] = v > 0.f ? v : 0.f;
  }
}

// ---------------------------------------------------------------------------
// agg[M,64] += (adj*alpha)[M,K] @ h[K,64]; deg[M] += rowsum(adj).
// A direct-to-reg (adj?alpha:0 -> bf16), B (h) staged fp32->bf16 in LDS
// as [col][k] (transposed) so frags read 8 consecutive k. Split-K + atomics.
// grid: (M/128, K/kChunk), block 256 (4 waves, 32 rows each)
// ---------------------------------------------------------------------------
__global__ __launch_bounds__(256, 2) void agg_kernel(
    const int* __restrict__ adj, int adjStride,
    const float* __restrict__ alpha, int alphaStride,
    const float* __restrict__ h, float* __restrict__ agg,
    float* __restrict__ deg, int kChunk)
{
  __shared__ ushort_t Bs[64 * 64];
  const int tid = threadIdx.x, lane = tid & 63, wave = tid >> 6;
  const int mb = blockIdx.x * 128;
  const int kStart = blockIdx.y * kChunk;
  const int rowBase = mb + wave * 32;

  f32x4 acc[2][4];
#pragma unroll
  for (int i = 0; i < 2; ++i)
#pragma unroll
    for (int j = 0; j < 4; ++j) acc[i][j] = f32x4{0.f, 0.f, 0.f, 0.f};
  int degAcc[2] = {0, 0};

  for (int k0 = kStart; k0 < kStart + kChunk; k0 += 64) {
    {   // stage h[k0..k0+64][0..64] -> Bs[c][k]
      int c = tid & 63, r0 = (tid >> 6) * 16;
#pragma unroll
      for (int half = 0; half < 2; ++half) {
        bf16x8 v;
#pragma unroll
        for (int j = 0; j < 8; ++j)
          v[j] = (short)bfu(h[(size_t)(k0 + r0 + half * 8 + j) * 64 + c]);
        int off = ((c * 64 + r0 + half * 8) << 1) ^ ((c & 7) << 4);
        *reinterpret_cast<bf16x8*>(reinterpret_cast<char*>(Bs) + off) = v;
      }
    }
    __syncthreads();
#pragma unroll
    for (int kk = 0; kk < 64; kk += 32) {
      int kb = (lane >> 4) << 3;
      int kg = k0 + kk + kb;
      bf16x8 af[2];
#pragma unroll
      for (int mf = 0; mf < 2; ++mf) {
        int row = rowBase + mf * 16 + (lane & 15);
        const int*   ap = adj   + (size_t)row * adjStride   + kg;
        const float* lp = alpha + (size_t)row * alphaStride + kg;
        int4 a0 = *(const int4*)ap;
        int4 a1 = *(const int4*)(ap + 4);
        float4 f0 = *(const float4*)lp;
        float4 f1 = *(const float4*)(lp + 4);
        degAcc[mf] += a0.x + a0.y + a0.z + a0.w + a1.x + a1.y + a1.z + a1.w;
        bf16x8 v;
        v[0] = a0.x ? (short)bfu(f0.x) : (short)0;
        v[1] = a0.y ? (short)bfu(f0.y) : (short)0;
        v[2] = a0.z ? (short)bfu(f0.z) : (short)0;
        v[3] = a0.w ? (short)bfu(f0.w) : (short)0;
        v[4] = a1.x ? (short)bfu(f1.x) : (short)0;
        v[5] = a1.y ? (short)bfu(f1.y) : (short)0;
        v[6] = a1.z ? (short)bfu(f1.z) : (short)0;
        v[7] = a1.w ? (short)bfu(f1.w) : (short)0;
        af[mf] = v;
      }
      bf16x8 br[4];
#pragma unroll
      for (int nf = 0; nf < 4; ++nf) {
        int c = nf * 16 + (lane & 15);
        int off = ((c * 64 + kk + kb) << 1) ^ ((c & 7) << 4);
        br[nf] = *reinterpret_cast<const bf16x8*>(reinterpret_cast<const char*>(Bs) + off);
      }
#pragma unroll
      for (int mf = 0; mf < 2; ++mf)
#pragma unroll
        for (int nf = 0; nf < 4; ++nf)
          acc[mf][nf] = mfma16(af[mf], br[nf], acc[mf][nf]);
    }
    __syncthreads();
  }
  // deg: reduce over the 4 quarter-wave k-groups, one atomic per row
#pragma unroll
  for (int mf = 0; mf < 2; ++mf) {
    int s = degAcc[mf];
    s += __shfl_xor(s, 16);
    s += __shfl_xor(s, 32);
    if (lane < 16) atomicAdd(&deg[rowBase + mf * 16 + lane], (float)s);
  }
#pragma unroll
  for (int mf = 0; mf < 2; ++mf)
#pragma unroll
    for (int nf = 0; nf < 4; ++nf) {
      int col = nf * 16 + (lane & 15);
      int rbase = rowBase + mf * 16 + ((lane >> 4) << 2);
#pragma unroll
      for (int i = 0; i < 4; ++i)
        atomicAdd(&agg[(size_t)(rbase + i) * 64 + col], acc[mf][nf][i]);
    }
}

// ---------------------------------------------------------------------------
// fused classifier: new = agg*W/deg + h ; logits[c] += dot(new, cw[c])
// ---------------------------------------------------------------------------
__global__ __launch_bounds__(256) void fused_dot(
    const float* __restrict__ agg1, const float* __restrict__ h1,
    const float* __restrict__ deg1,
    const float* __restrict__ agg2, const float* __restrict__ h2,
    const float* __restrict__ deg2,
    const float* __restrict__ Wp, const float* __restrict__ cw,
    float* __restrict__ logits)
{
  const float w00 = Wp[0];
  const int n1 = 8192 * 64;
  const int ntot = (8192 + 4096) * 64;
  float a0 = 0.f, a1 = 0.f;
  for (int j = blockIdx.x * 256 + threadIdx.x; j < ntot;
       j += gridDim.x * 256) {
    float v;
    if (j < n1) {
      v = agg1[j] * w00 / deg1[j >> 6] + h1[j];
    } else {
      int j2 = j - n1;
      v = agg2[j2] * w00 / deg2[j2 >> 6] + h2[j2];
    }
    a0 += v * cw[j];
    a1 += v * cw[ntot + j];
  }
#pragma unroll
  for (int o = 32; o > 0; o >>= 1) {
    a0 += __shfl_down(a0, o);
    a1 += __shfl_down(a1, o);
  }
  __shared__ float s0[4], s1[4];
  int lane = threadIdx.x & 63, wave = threadIdx.x >> 6;
  if (lane == 0) { s0[wave] = a0; s1[wave] = a1; }
  __syncthreads();
  if (threadIdx.x == 0) {
    atomicAdd(&logits[0], s0[0] + s0[1] + s0[2] + s0[3]);
    atomicAdd(&logits[1], s1[0] + s1[1] + s1[2] + s1[3]);
  }
}

__global__ void finalize(const float* __restrict__ logits,
                         const float* __restrict__ cb, float* __restrict__ out)
{
  if (threadIdx.x == 0) {
    float l0 = logits[0] + cb[0];
    float l1 = logits[1] + cb[1];
    float m = fmaxf(l0, l1);
    float e0 = expf(l0 - m), e1 = expf(l1 - m);
    float inv = 1.f / (e0 + e1);
    out[0] = e0 * inv;
    out[1] = e1 * inv;
  }
}

// ---------------------------------------------------------------------------
extern "C" void kernel_launch(void* const* d_in, const int* in_sizes, int n_in,
                              void* d_out, int out_size, void* d_ws,
                              size_t ws_size, hipStream_t stream)
{
  const float* x1    = (const float*)d_in[0];
  const float* x2    = (const float*)d_in[1];
  const int*   adj1  = (const int*)d_in[2];
  const int*   adj2  = (const int*)d_in[3];
  const float* p1w1  = (const float*)d_in[4];
  const float* p1g1  = (const float*)d_in[6];
  const float* p1be1 = (const float*)d_in[7];
  const float* p1w2  = (const float*)d_in[8];
  const float* p1g2  = (const float*)d_in[10];
  const float* p1be2 = (const float*)d_in[11];
  const float* p1w3  = (const float*)d_in[12];
  const float* p1g3  = (const float*)d_in[14];
  const float* p1be3 = (const float*)d_in[15];
  const float* p2w1  = (const float*)d_in[16];
  const float* p2g1  = (const float*)d_in[18];
  const float* p2be1 = (const float*)d_in[19];
  const float* p2w2  = (const float*)d_in[20];
  const float* p2g2  = (const float*)d_in[22];
  const float* p2be2 = (const float*)d_in[23];
  const float* p2w3  = (const float*)d_in[24];
  const float* p2g3  = (const float*)d_in[26];
  const float* p2be3 = (const float*)d_in[27];
  const float* Wp     = (const float*)d_in[28];
  const float* alpha1 = (const float*)d_in[29];
  const float* cw     = (const float*)d_in[31];
  const float* cb     = (const float*)d_in[32];
  float* out = (float*)d_out;

  // workspace layout — everything is in one contiguous zero-init region
  // because split-K GEMMs and agg/deg/stats/logits all accumulate atomically.
  float* w    = (float*)d_ws;
  float* H1a  = w;                  // 8192*256 = 2097152
  float* H2a  = H1a + 2097152;      // 4096*256 = 1048576
  float* H1b  = H2a + 1048576;      // 8192*128 = 1048576
  float* h1   = H1b + 1048576;      // 8192*64  = 524288
  float* H2b  = h1  + 524288;       // 4096*128 = 524288
  float* h2   = H2b + 524288;       // 4096*64  = 262144
  float* agg1 = h2  + 262144;       // 524288
  float* agg2 = agg1 + 524288;      // 262144
  float* deg1 = agg2 + 262144;      // 8192
  float* deg2 = deg1 + 8192;        // 4096
  float* st   = deg2 + 4096;        // 6*512 = 3072
  float* logits = st + 3072;        // 8

  size_t zeroBytes = (size_t)(2097152 + 1048576 + 1048576 + 524288 + 524288 +
                              262144 + 524288 + 262144 + 8192 + 4096 + 3072 + 8) * 4;
  hipMemsetAsync(w, 0, zeroBytes, stream);

  // ---- branch 1 encoder (split-K everywhere for >=2 blocks/CU) ----
  gemm_bf16<<<dim3(64, 4, 8), 256, 0, stream>>>(x1, p1w1, H1a, 8192, 256, 8192, 1024);
  col_stats<<<dim3(4, 32), 256, 0, stream>>>(H1a, st + 0 * 512, 8192, 256);
  bn_apply<<<2048, 256, 0, stream>>>(H1a, st + 0 * 512, p1g1, p1be1, 8192, 256);
  gemm_bf16<<<dim3(64, 2, 2), 256, 0, stream>>>(H1a, p1w2, H1b, 8192, 128, 256, 128);
  col_stats<<<dim3(2, 32), 256, 0, stream>>>(H1b, st + 1 * 512, 8192, 128);
  bn_apply<<<1024, 256, 0, stream>>>(H1b, st + 1 * 512, p1g2, p1be2, 8192, 128);
  gemm_bf16<<<dim3(64, 1, 2), 256, 0, stream>>>(H1b, p1w3, h1, 8192, 64, 128, 64);
  col_stats<<<dim3(1, 32), 256, 0, stream>>>(h1, st + 2 * 512, 8192, 64);
  bn_apply<<<512, 256, 0, stream>>>(h1, st + 2 * 512, p1g3, p1be3, 8192, 64);

  // ---- branch 2 encoder ----
  gemm_bf16<<<dim3(32, 4, 4), 256, 0, stream>>>(x2, p2w1, H2a, 4096, 256, 4096, 1024);
  col_stats<<<dim3(4, 16), 256, 0, stream>>>(H2a, st + 3 * 512, 4096, 256);
  bn_apply<<<1024, 256, 0, stream>>>(H2a, st + 3 * 512, p2g1, p2be1, 4096, 256);
  gemm_bf16<<<dim3(32, 2, 2), 256, 0, stream>>>(H2a, p2w2, H2b, 4096, 128, 256, 128);
  col_stats<<<dim3(2, 16), 256, 0, stream>>>(H2b, st + 4 * 512, 4096, 128);
  bn_apply<<<512, 256, 0, stream>>>(H2b, st + 4 * 512, p2g2, p2be2, 4096, 128);
  gemm_bf16<<<dim3(32, 1, 2), 256, 0, stream>>>(H2b, p2w3, h2, 4096, 64, 128, 64);
  col_stats<<<dim3(1, 16), 256, 0, stream>>>(h2, st + 5 * 512, 4096, 64);
  bn_apply<<<256, 256, 0, stream>>>(h2, st + 5 * 512, p2g3, p2be3, 4096, 64);

  // ---- attention aggregation (fused deg) ----
  agg_kernel<<<dim3(64, 4), 256, 0, stream>>>(adj1, 8192, alpha1, 8192,
                                              h1, agg1, deg1, 2048);
  // NB: reference reuses alpha1[:4096,:4096] for graph 2 (source bug kept)
  agg_kernel<<<dim3(32, 8), 256, 0, stream>>>(adj2, 4096, alpha1, 8192,
                                              h2, agg2, deg2, 512);

  // ---- fused classifier + softmax ----
  fused_dot<<<1024, 256, 0, stream>>>(agg1, h1, deg1, agg2, h2, deg2,
                                      Wp, cw, logits);
  finalize<<<1, 64, 0, stream>>>(logits, cb, out);
}